// Round 9
// baseline (1382.626 us; speedup 1.0000x reference)
//
#include <hip/hip_runtime.h>

#define IN_C 128
#define HID_C 128
#define OUT_C 64

#define BSPAN 256        // dst nodes per bucket
#define BCAP  5120       // edge capacity per bucket (mean 4096 + 16 sigma)
#define NBMAX 512        // max buckets (requires N <= 131072 for 17-bit src pack)
#define ACHUNK 2048      // edges per bin chunk
#define GRID 1024        // 4 blocks/CU on 256 CUs -- co-resident by construction

typedef unsigned int uint32;
typedef unsigned short ushort16;
typedef _Float16 f16;
typedef f16   f16x8 __attribute__((ext_vector_type(8)));
typedef float f32x4 __attribute__((ext_vector_type(4)));

// ---------------- helpers ----------------

__device__ __forceinline__ ushort16 f2bf(float f) {
    union { float f; uint32 u; } v; v.f = f;
    uint32 r = v.u + 0x7FFFu + ((v.u >> 16) & 1u);   // round-to-nearest-even
    return (ushort16)(r >> 16);
}

__device__ __forceinline__ void unpack2(uint32 u, float& f0, float& f1) {
    union { uint32 x; float f; } a, b;
    a.x = u << 16;
    b.x = u & 0xFFFF0000u;
    f0 = a.f; f1 = b.f;
}

__device__ __forceinline__ void acc_row(uint4 r, float* acc) {
    float f0, f1;
    unpack2(r.x, f0, f1); acc[0] += f0; acc[1] += f1;
    unpack2(r.y, f0, f1); acc[2] += f0; acc[3] += f1;
    unpack2(r.z, f0, f1); acc[4] += f0; acc[5] += f1;
    unpack2(r.w, f0, f1); acc[6] += f0; acc[7] += f1;
}

// device-scope software grid barrier; counters pre-zeroed by hipMemsetAsync.
__device__ __forceinline__ void gbar(int* c) {
    __syncthreads();
    if (threadIdx.x == 0) {
        __threadfence();                                   // release prior writes
        __hip_atomic_fetch_add(c, 1, __ATOMIC_RELEASE, __HIP_MEMORY_SCOPE_AGENT);
        while (__hip_atomic_load(c, __ATOMIC_ACQUIRE, __HIP_MEMORY_SCOPE_AGENT) < GRID)
            __builtin_amdgcn_s_sleep(8);
        __threadfence();
    }
    __syncthreads();
}

// W -> MFMA B-fragment layout (fp16)
template <int C>
__device__ __forceinline__ void wprep_one(const float* __restrict__ W, f16* __restrict__ Wf, int t) {
    constexpr int NCT = C / 16;
    int lane = t & 63;
    int ctkc = t >> 6;
    int ct = ctkc % NCT, kc = ctkc / NCT;
    int kbase = kc * 32 + (lane >> 4) * 8;
    int col   = ct * 16 + (lane & 15);
    f16 v[8];
#pragma unroll
    for (int j = 0; j < 8; j++) v[j] = (f16)W[(size_t)(kbase + j) * C + col];
    *(uint4*)(Wf + (size_t)t * 8) = *(const uint4*)v;
}

// ---------------- the mega kernel ----------------

union SMem {
    struct { int hist[NBMAX]; int base[NBMAX]; } p1;          // 4 KB
    struct { int cnt[BSPAN]; int scn[BSPAN]; int ex[BSPAN]; } p2;  // 3 KB
    f16 As[4 * 4 * 64 * 8];                                    // 16 KB
};

__launch_bounds__(256, 4)
__global__ void mega_kernel(const float* __restrict__ x, const int* __restrict__ src,
                            const int* __restrict__ dst,
                            const float* __restrict__ W1, const float* __restrict__ b1,
                            const float* __restrict__ W2, const float* __restrict__ b2,
                            float* __restrict__ out,
                            int* __restrict__ bucketCur, float* __restrict__ inv,
                            int* __restrict__ rowbeg, int* __restrict__ rowend,
                            uint32* __restrict__ binned, int* __restrict__ csrs,
                            f16* __restrict__ Wf1, f16* __restrict__ Wf2,
                            ushort16* __restrict__ hs1b, ushort16* __restrict__ hs2b,
                            int* __restrict__ bars,
                            int N, int E, int nbuck, int nchunk) {
    __shared__ __align__(16) SMem sm;
    const int tid  = threadIdx.x;
    const int lane = tid & 63;
    const int w    = tid >> 6;

    // ================= P0: weight swizzle + bucketCur zero =================
    {
        int gid = blockIdx.x * 256 + tid;
        if (gid < nbuck) bucketCur[gid] = 0;
        constexpr int T1 = 4 * (HID_C / 16) * 64;   // 2048
        constexpr int T2 = 4 * (OUT_C / 16) * 64;   // 1024
        if (gid < T1)           wprep_one<HID_C>(W1, Wf1, gid);
        else if (gid < T1 + T2) wprep_one<OUT_C>(W2, Wf2, gid - T1);
    }
    gbar(&bars[0]);

    // ================= P1: bin edges by dst bucket =================
    for (int ch = blockIdx.x; ch < nchunk; ch += GRID) {
        for (int i = tid; i < NBMAX; i += 256) sm.p1.hist[i] = 0;
        __syncthreads();
        const int e0 = ch * ACHUNK;
        int d[8], s[8], rk[8];
#pragma unroll
        for (int j = 0; j < 8; j++) {
            int e = e0 + j * 256 + tid;
            if (e < E) {
                d[j] = dst[e];
                s[j] = src[e];
                rk[j] = atomicAdd(&sm.p1.hist[d[j] >> 8], 1);
            } else d[j] = -1;
        }
        __syncthreads();
        for (int b = tid; b < nbuck; b += 256) {
            int h = sm.p1.hist[b];
            sm.p1.base[b] = h ? atomicAdd(&bucketCur[b], h) : 0;
        }
        __syncthreads();
#pragma unroll
        for (int j = 0; j < 8; j++) {
            if (d[j] >= 0) {
                int b = d[j] >> 8;
                int pos = sm.p1.base[b] + rk[j];
                if (pos < BCAP)
                    binned[(size_t)b * BCAP + pos] =
                        ((uint32)(d[j] & 255) << 17) | (uint32)s[j];
            }
        }
        __syncthreads();
    }
    gbar(&bars[1]);

    // ================= P2: per-bucket CSR + degree + inv =================
    for (int b = blockIdx.x; b < nbuck; b += GRID) {
        sm.p2.cnt[tid] = 0;
        __syncthreads();
        const int ne = min(bucketCur[b], BCAP);
        const uint32* bp = binned + (size_t)b * BCAP;

        int rbuf[BCAP / 256];          // 20 ranks max
        int nm = 0;
        for (int i = tid; i < ne; i += 256)
            rbuf[nm++] = atomicAdd(&sm.p2.cnt[bp[i] >> 17], 1);
        __syncthreads();

        int v = sm.p2.cnt[tid];
        sm.p2.scn[tid] = v;
        __syncthreads();
        for (int off = 1; off < 256; off <<= 1) {
            int u = (tid >= off) ? sm.p2.scn[tid - off] : 0;
            __syncthreads();
            sm.p2.scn[tid] += u;
            __syncthreads();
        }
        int ex = sm.p2.scn[tid] - v;
        sm.p2.ex[tid] = ex;

        int n = b * BSPAN + tid;
        if (n < N) {
            int gb = b * BCAP + ex;
            rowbeg[n] = gb;
            rowend[n] = gb + v;
            inv[n] = rsqrtf((float)(v + 1));   // +1 self-loop
        }
        __syncthreads();

        nm = 0;
        for (int i = tid; i < ne; i += 256) {
            uint32 e = bp[i];   // L2-hot re-read
            csrs[(size_t)b * BCAP + sm.p2.ex[e >> 17] + rbuf[nm++]] = (int)(e & 0x1FFFFu);
        }
        __syncthreads();
    }
    gbar(&bars[2]);

    // ================= P3: gemm1  hs1b = bf16(inv * (x @ W1)) =================
    {
        const int ntile = (N + 63) / 64;
        for (int t = blockIdx.x; t < ntile; t += GRID) {
            const int row0 = t * 64;
            __syncthreads();           // As free from previous iteration
            {   // stage X tile -> As (fragment-major)
                int r   = tid >> 2;
                int seg = tid & 3;
                int row = row0 + r;
                int ws_ = r >> 4;
                int r15 = r & 15;
#pragma unroll
                for (int i = 0; i < 8; i++) {
                    int k = seg * 32 + i * 4;
                    float4 v = make_float4(0.f, 0.f, 0.f, 0.f);
                    if (row < N) v = *(const float4*)(x + (size_t)row * 128 + k);
                    int q = (k >> 3) & 3, j0 = k & 7;
                    f16 h[4] = {(f16)v.x, (f16)v.y, (f16)v.z, (f16)v.w};
                    int slot = ((seg * 4 + ws_) * 64 + (q * 16 + r15)) * 8 + j0;
                    *(uint2*)(sm.As + slot) = *(const uint2*)h;
                }
            }
            __syncthreads();

            f32x4 acc[8];
#pragma unroll
            for (int c = 0; c < 8; c++) acc[c] = (f32x4){0.f, 0.f, 0.f, 0.f};
#pragma unroll
            for (int kc = 0; kc < 4; kc++) {
                f16x8 a = *(const f16x8*)&sm.As[((kc * 4 + w) * 64 + lane) * 8];
#pragma unroll
                for (int ct = 0; ct < 8; ct++) {
                    f16x8 b = *(const f16x8*)&Wf1[(size_t)(((kc * 8 + ct) * 64) + lane) * 8];
                    acc[ct] = __builtin_amdgcn_mfma_f32_16x16x32_f16(a, b, acc[ct], 0, 0, 0);
                }
            }

            __syncthreads();
            ushort16* Ds = (ushort16*)sm.As;   // [64][128]
            const int q = lane >> 4;
            float iv[4];
#pragma unroll
            for (int reg = 0; reg < 4; reg++) {
                int row = row0 + w * 16 + q * 4 + reg;
                iv[reg] = (row < N) ? inv[row] : 0.f;
            }
#pragma unroll
            for (int ct = 0; ct < 8; ct++)
#pragma unroll
                for (int reg = 0; reg < 4; reg++) {
                    int r = w * 16 + q * 4 + reg;
                    Ds[r * 128 + ct * 16 + (lane & 15)] = f2bf(acc[ct][reg] * iv[reg]);
                }
            __syncthreads();
            {
                int r   = tid >> 2;
                int row = row0 + r;
                if (row < N) {
                    int c0 = (tid & 3) * 32;
                    const uint4* s = (const uint4*)&Ds[r * 128 + c0];
                    uint4* d = (uint4*)(hs1b + (size_t)row * 128 + c0);
#pragma unroll
                    for (int i = 0; i < 4; i++) d[i] = s[i];
                }
            }
        }
    }
    gbar(&bars[3]);

    // ================= P4: fused gather1(+relu) -> GEMM2 -> hs2b =================
    {
        const int ntile = (N + 63) / 64;
        for (int t = blockIdx.x; t < ntile; t += GRID) {
            const int row0 = t * 64;
            __syncthreads();
            {   // gather phase: thread = (node r, quarter q), 32 channels each
                int r = tid >> 2;
                int q = tid & 3;
                int n = row0 + r;
                float acc[32];
#pragma unroll
                for (int j = 0; j < 32; j++) acc[j] = 0.f;

                if (n < N) {
                    const ushort16* base = hs1b + (size_t)n * 128 + q * 32;
                    uint4 s0 = *(const uint4*)(base);
                    uint4 s1 = *(const uint4*)(base + 8);
                    uint4 s2 = *(const uint4*)(base + 16);
                    uint4 s3 = *(const uint4*)(base + 24);
                    acc_row(s0, acc); acc_row(s1, acc + 8);
                    acc_row(s2, acc + 16); acc_row(s3, acc + 24);

                    int beg = rowbeg[n], end = rowend[n];
                    int i = beg;
                    for (; i + 2 <= end; i += 2) {
                        const ushort16* p0 = hs1b + (size_t)csrs[i]     * 128 + q * 32;
                        const ushort16* p1 = hs1b + (size_t)csrs[i + 1] * 128 + q * 32;
                        uint4 a0 = *(const uint4*)(p0);
                        uint4 a1 = *(const uint4*)(p0 + 8);
                        uint4 a2 = *(const uint4*)(p0 + 16);
                        uint4 a3 = *(const uint4*)(p0 + 24);
                        uint4 c0 = *(const uint4*)(p1);
                        uint4 c1 = *(const uint4*)(p1 + 8);
                        uint4 c2 = *(const uint4*)(p1 + 16);
                        uint4 c3 = *(const uint4*)(p1 + 24);
                        acc_row(a0, acc); acc_row(a1, acc + 8);
                        acc_row(a2, acc + 16); acc_row(a3, acc + 24);
                        acc_row(c0, acc); acc_row(c1, acc + 8);
                        acc_row(c2, acc + 16); acc_row(c3, acc + 24);
                    }
                    if (i < end) {
                        const ushort16* p0 = hs1b + (size_t)csrs[i] * 128 + q * 32;
                        uint4 a0 = *(const uint4*)(p0);
                        uint4 a1 = *(const uint4*)(p0 + 8);
                        uint4 a2 = *(const uint4*)(p0 + 16);
                        uint4 a3 = *(const uint4*)(p0 + 24);
                        acc_row(a0, acc); acc_row(a1, acc + 8);
                        acc_row(a2, acc + 16); acc_row(a3, acc + 24);
                    }

                    float ivn = inv[n];
#pragma unroll
                    for (int j = 0; j < 32; j++)
                        acc[j] = fmaxf(fmaf(ivn, acc[j], b1[q * 32 + j]), 0.f);
                }

                int ws_ = r >> 4, r15 = r & 15;
#pragma unroll
                for (int i8 = 0; i8 < 4; i8++) {
                    f16 h[8];
#pragma unroll
                    for (int j = 0; j < 8; j++) h[j] = (f16)acc[i8 * 8 + j];
                    int slot = ((q * 4 + ws_) * 64 + (i8 * 16 + r15)) * 8;
                    *(uint4*)(sm.As + slot) = *(const uint4*)h;
                }
            }
            __syncthreads();

            f32x4 acc2[4];
#pragma unroll
            for (int c = 0; c < 4; c++) acc2[c] = (f32x4){0.f, 0.f, 0.f, 0.f};
#pragma unroll
            for (int kc = 0; kc < 4; kc++) {
                f16x8 a = *(const f16x8*)&sm.As[((kc * 4 + w) * 64 + lane) * 8];
#pragma unroll
                for (int ct = 0; ct < 4; ct++) {
                    f16x8 b = *(const f16x8*)&Wf2[(size_t)(((kc * 4 + ct) * 64) + lane) * 8];
                    acc2[ct] = __builtin_amdgcn_mfma_f32_16x16x32_f16(a, b, acc2[ct], 0, 0, 0);
                }
            }

            __syncthreads();
            ushort16* Ds = (ushort16*)sm.As;   // [64][64]
            const int q2 = lane >> 4;
            float iv2[4];
#pragma unroll
            for (int reg = 0; reg < 4; reg++) {
                int row = row0 + w * 16 + q2 * 4 + reg;
                iv2[reg] = (row < N) ? inv[row] : 0.f;
            }
#pragma unroll
            for (int ct = 0; ct < 4; ct++)
#pragma unroll
                for (int reg = 0; reg < 4; reg++) {
                    int r = w * 16 + q2 * 4 + reg;
                    Ds[r * 64 + ct * 16 + (lane & 15)] = f2bf(acc2[ct][reg] * iv2[reg]);
                }
            __syncthreads();
            {
                int r   = tid >> 2;
                int row = row0 + r;
                if (row < N) {
                    int c0 = (tid & 3) * 16;
                    const uint4* s = (const uint4*)&Ds[r * 64 + c0];
                    uint4* d = (uint4*)(hs2b + (size_t)row * 64 + c0);
#pragma unroll
                    for (int i = 0; i < 2; i++) d[i] = s[i];
                }
            }
        }
    }
    gbar(&bars[4]);

    // ================= P5: final gather (layer 2) -> fp32 out =================
    {
        const int ngrp = (N + 31) / 32;
        for (int g = blockIdx.x; g < ngrp; g += GRID) {
            int n    = g * 32 + (tid >> 3);
            int lan8 = tid & 7;
            if (n < N) {
                int c8 = lan8 * 8;
                float acc[8];
                {
                    uint4 raw = *(const uint4*)(hs2b + (size_t)n * 64 + c8);
                    unpack2(raw.x, acc[0], acc[1]);
                    unpack2(raw.y, acc[2], acc[3]);
                    unpack2(raw.z, acc[4], acc[5]);
                    unpack2(raw.w, acc[6], acc[7]);
                }
                int beg = rowbeg[n];
                int end = rowend[n];
                int i = beg;
                for (; i + 4 <= end; i += 4) {
                    uint4 r0 = *(const uint4*)(hs2b + (size_t)csrs[i]     * 64 + c8);
                    uint4 r1 = *(const uint4*)(hs2b + (size_t)csrs[i + 1] * 64 + c8);
                    uint4 r2 = *(const uint4*)(hs2b + (size_t)csrs[i + 2] * 64 + c8);
                    uint4 r3 = *(const uint4*)(hs2b + (size_t)csrs[i + 3] * 64 + c8);
                    acc_row(r0, acc); acc_row(r1, acc); acc_row(r2, acc); acc_row(r3, acc);
                }
                for (; i < end; i++) {
                    uint4 r0 = *(const uint4*)(hs2b + (size_t)csrs[i] * 64 + c8);
                    acc_row(r0, acc);
                }
                float iv = inv[n];
                float4 v0 = *(const float4*)(b2 + c8);
                float4 v1 = *(const float4*)(b2 + c8 + 4);
                float r[8];
                r[0] = fmaf(iv, acc[0], v0.x); r[1] = fmaf(iv, acc[1], v0.y);
                r[2] = fmaf(iv, acc[2], v0.z); r[3] = fmaf(iv, acc[3], v0.w);
                r[4] = fmaf(iv, acc[4], v1.x); r[5] = fmaf(iv, acc[5], v1.y);
                r[6] = fmaf(iv, acc[6], v1.z); r[7] = fmaf(iv, acc[7], v1.w);
                float* po = out + (size_t)n * 64 + c8;
                *(float4*)(po)     = make_float4(r[0], r[1], r[2], r[3]);
                *(float4*)(po + 4) = make_float4(r[4], r[5], r[6], r[7]);
            }
        }
    }
}

extern "C" void kernel_launch(void* const* d_in, const int* in_sizes, int n_in,
                              void* d_out, int out_size, void* d_ws, size_t ws_size,
                              hipStream_t stream) {
    const float* x  = (const float*)d_in[0];
    const int*   ei = (const int*)d_in[1];
    const float* W1 = (const float*)d_in[2];
    const float* b1 = (const float*)d_in[3];
    const float* W2 = (const float*)d_in[4];
    const float* b2 = (const float*)d_in[5];
    float* out = (float*)d_out;

    const int N = in_sizes[0] / IN_C;    // 100000 (<= 131072 for src packing)
    const int E = in_sizes[1] / 2;       // 1600000
    const int* src = ei;
    const int* dst = ei + E;
    const int nbuck  = (N + BSPAN - 1) / BSPAN;     // 391
    const int nchunk = (E + ACHUNK - 1) / ACHUNK;   // 782

    // workspace layout
    char* ws = (char*)d_ws;
    auto align_up = [](size_t v) { return (v + 1023) & ~(size_t)1023; };
    size_t off = 0;
    int*      bars      = (int*)(ws + off);      off += align_up(8 * sizeof(int));
    int*      bucketCur = (int*)(ws + off);      off += align_up((size_t)nbuck * sizeof(int));
    float*    inv       = (float*)(ws + off);    off += align_up((size_t)N * sizeof(float));
    int*      rowbeg    = (int*)(ws + off);      off += align_up((size_t)N * sizeof(int));
    int*      rowend    = (int*)(ws + off);      off += align_up((size_t)N * sizeof(int));
    uint32*   binned    = (uint32*)(ws + off);   off += align_up((size_t)nbuck * BCAP * sizeof(uint32));
    int*      csrs      = (int*)(ws + off);      off += align_up((size_t)nbuck * BCAP * sizeof(int));
    f16*      Wf1       = (f16*)(ws + off);      off += align_up((size_t)4 * (HID_C/16) * 64 * 8 * sizeof(f16));
    f16*      Wf2       = (f16*)(ws + off);      off += align_up((size_t)4 * (OUT_C/16) * 64 * 8 * sizeof(f16));
    ushort16* hs1b      = (ushort16*)(ws + off); off += align_up((size_t)N * HID_C * sizeof(ushort16));
    ushort16* hs2b      = (ushort16*)(ws + off); off += align_up((size_t)N * OUT_C * sizeof(ushort16));

    // zero the barrier counters, then one persistent kernel does everything
    hipMemsetAsync(bars, 0, 8 * sizeof(int), stream);
    mega_kernel<<<GRID, 256, 0, stream>>>(
        x, src, dst, W1, b1, W2, b2, out,
        bucketCur, inv, rowbeg, rowend, binned, csrs, Wf1, Wf2, hs1b, hs2b, bars,
        N, E, nbuck, nchunk);
}

// Round 10
// 269.631 us; speedup vs baseline: 5.1279x; 5.1279x over previous
//
#include <hip/hip_runtime.h>

#define IN_C 128
#define HID_C 128
#define OUT_C 64

#define BSPAN 256        // dst nodes per bucket
#define BCAP  5120       // edge capacity per bucket (mean 4096 + 16 sigma)
#define NBMAX 512        // max buckets (requires N <= 131072 for 17-bit src pack)
#define ACHUNK 4096      // edges per bin chunk

typedef unsigned int uint32;
typedef unsigned short ushort16;
typedef _Float16 f16;
typedef f16   f16x8 __attribute__((ext_vector_type(8)));
typedef float f32x4 __attribute__((ext_vector_type(4)));

// ---------------- helpers ----------------

__device__ __forceinline__ ushort16 f2bf(float f) {
    union { float f; uint32 u; } v; v.f = f;
    uint32 r = v.u + 0x7FFFu + ((v.u >> 16) & 1u);   // round-to-nearest-even
    return (ushort16)(r >> 16);
}

__device__ __forceinline__ void unpack2(uint32 u, float& f0, float& f1) {
    union { uint32 x; float f; } a, b;
    a.x = u << 16;
    b.x = u & 0xFFFF0000u;
    f0 = a.f; f1 = b.f;
}

__device__ __forceinline__ void acc_row(uint4 r, float* acc) {
    float f0, f1;
    unpack2(r.x, f0, f1); acc[0] += f0; acc[1] += f1;
    unpack2(r.y, f0, f1); acc[2] += f0; acc[3] += f1;
    unpack2(r.z, f0, f1); acc[4] += f0; acc[5] += f1;
    unpack2(r.w, f0, f1); acc[6] += f0; acc[7] += f1;
}

// scaled accumulate: acc += s * row
__device__ __forceinline__ void acc_row_s(uint4 r, float s, float* acc) {
    float f0, f1;
    unpack2(r.x, f0, f1); acc[0] = fmaf(s, f0, acc[0]); acc[1] = fmaf(s, f1, acc[1]);
    unpack2(r.y, f0, f1); acc[2] = fmaf(s, f0, acc[2]); acc[3] = fmaf(s, f1, acc[3]);
    unpack2(r.z, f0, f1); acc[4] = fmaf(s, f0, acc[4]); acc[5] = fmaf(s, f1, acc[5]);
    unpack2(r.w, f0, f1); acc[6] = fmaf(s, f0, acc[6]); acc[7] = fmaf(s, f1, acc[7]);
}

// W -> MFMA B-fragment layout (fp16)
template <int C>
__device__ __forceinline__ void wprep_one(const float* __restrict__ W, f16* __restrict__ Wf, int t) {
    constexpr int NCT = C / 16;
    int lane = t & 63;
    int ctkc = t >> 6;
    int ct = ctkc % NCT, kc = ctkc / NCT;
    int kbase = kc * 32 + (lane >> 4) * 8;
    int col   = ct * 16 + (lane & 15);
    f16 v[8];
#pragma unroll
    for (int j = 0; j < 8; j++) v[j] = (f16)W[(size_t)(kbase + j) * C + col];
    *(uint4*)(Wf + (size_t)t * 8) = *(const uint4*)v;
}

// ================= K1: bin edges by dst bucket  +  weight swizzle =================
// blocks [0, nchunk): binning; blocks [nchunk, nchunk+12): wprep for W1 & W2.

__launch_bounds__(256)
__global__ void k1_bin_wprep(const int* __restrict__ src, const int* __restrict__ dst,
                             int* __restrict__ bucketCur, uint32* __restrict__ binned,
                             const float* __restrict__ W1, f16* __restrict__ Wf1,
                             const float* __restrict__ W2, f16* __restrict__ Wf2,
                             int E, int nbuck, int nchunk) {
    const int tid = threadIdx.x;
    if ((int)blockIdx.x >= nchunk) {
        int t = ((int)blockIdx.x - nchunk) * 256 + tid;
        constexpr int T1 = 4 * (HID_C / 16) * 64;   // 2048
        constexpr int T2 = 4 * (OUT_C / 16) * 64;   // 1024
        if (t < T1)           wprep_one<HID_C>(W1, Wf1, t);
        else if (t < T1 + T2) wprep_one<OUT_C>(W2, Wf2, t - T1);
        return;
    }
    __shared__ int hist[NBMAX];
    __shared__ int base[NBMAX];
    const int e0 = blockIdx.x * ACHUNK;

    for (int i = tid; i < NBMAX; i += 256) hist[i] = 0;
    __syncthreads();

    int d[16], s[16], rk[16];
#pragma unroll
    for (int j = 0; j < 16; j++) {
        int e = e0 + j * 256 + tid;
        if (e < E) {
            d[j] = dst[e];
            s[j] = src[e];
            rk[j] = atomicAdd(&hist[d[j] >> 8], 1);
        } else d[j] = -1;
    }
    __syncthreads();

    for (int b = tid; b < nbuck; b += 256) {
        int h = hist[b];
        base[b] = h ? atomicAdd(&bucketCur[b], h) : 0;
    }
    __syncthreads();

#pragma unroll
    for (int j = 0; j < 16; j++) {
        if (d[j] >= 0) {
            int b = d[j] >> 8;
            int pos = base[b] + rk[j];
            if (pos < BCAP)
                binned[(size_t)b * BCAP + pos] =
                    ((uint32)(d[j] & 255) << 17) | (uint32)s[j];
        }
    }
}

// ================= K2: per-bucket CSR (+inv)  ||  GEMM1 (raw h-tilde) =================
// blocks [0, nbuck): bucket CSR; blocks [nbuck, nbuck+ntile): gemm1 tiles.
// gemm1 does NOT scale by inv (dependency broken); Wf1 B-frags read from global (L1/L2-hot).

__launch_bounds__(256)
__global__ void k2_csr_gemm1(const uint32* __restrict__ binned, const int* __restrict__ bucketCur,
                             int* __restrict__ csrs, int* __restrict__ rowbeg,
                             int* __restrict__ rowend, float* __restrict__ inv,
                             const float* __restrict__ x, const f16* __restrict__ Wf1,
                             ushort16* __restrict__ hs1b, int N, int nbuck) {
    __shared__ __align__(16) f16 As[4 * 4 * 64 * 8];   // 16 KB; csr path reuses as int scratch
    const int tid = threadIdx.x;

    if ((int)blockIdx.x < nbuck) {
        // ---- bucket CSR ----
        int* cnt = (int*)As;
        int* scn = cnt + BSPAN;
        int* ex  = scn + BSPAN;
        const int b  = blockIdx.x;
        const int ne = min(bucketCur[b], BCAP);
        const uint32* bp = binned + (size_t)b * BCAP;

        cnt[tid] = 0;
        __syncthreads();

        int rbuf[BCAP / 256];          // 20 ranks max
        int nm = 0;
        for (int i = tid; i < ne; i += 256)
            rbuf[nm++] = atomicAdd(&cnt[bp[i] >> 17], 1);
        __syncthreads();

        int v = cnt[tid];
        scn[tid] = v;
        __syncthreads();
        for (int off = 1; off < 256; off <<= 1) {
            int u = (tid >= off) ? scn[tid - off] : 0;
            __syncthreads();
            scn[tid] += u;
            __syncthreads();
        }
        int e0 = scn[tid] - v;
        ex[tid] = e0;

        int n = b * BSPAN + tid;
        if (n < N) {
            int gb = b * BCAP + e0;
            rowbeg[n] = gb;
            rowend[n] = gb + v;
            inv[n] = rsqrtf((float)(v + 1));   // +1 self-loop
        }
        __syncthreads();

        nm = 0;
        for (int i = tid; i < ne; i += 256) {
            uint32 e = bp[i];   // L2-hot re-read
            csrs[(size_t)b * BCAP + ex[e >> 17] + rbuf[nm++]] = (int)(e & 0x1FFFFu);
        }
        return;
    }

    // ---- gemm1: hs1b = bf16(x @ W1), raw (no inv) ----
    const int lane = tid & 63;
    const int w    = tid >> 6;
    const int row0 = ((int)blockIdx.x - nbuck) * 64;

    {   // stage X tile -> As (fragment-major)
        int r   = tid >> 2;
        int seg = tid & 3;
        int row = row0 + r;
        int ws_ = r >> 4;
        int r15 = r & 15;
#pragma unroll
        for (int i = 0; i < 8; i++) {
            int k = seg * 32 + i * 4;
            float4 v = make_float4(0.f, 0.f, 0.f, 0.f);
            if (row < N) v = *(const float4*)(x + (size_t)row * 128 + k);
            int q = (k >> 3) & 3, j0 = k & 7;
            f16 h[4] = {(f16)v.x, (f16)v.y, (f16)v.z, (f16)v.w};
            int slot = ((seg * 4 + ws_) * 64 + (q * 16 + r15)) * 8 + j0;
            *(uint2*)(As + slot) = *(const uint2*)h;
        }
    }
    __syncthreads();

    f32x4 acc[8];
#pragma unroll
    for (int c = 0; c < 8; c++) acc[c] = (f32x4){0.f, 0.f, 0.f, 0.f};
#pragma unroll
    for (int kc = 0; kc < 4; kc++) {
        f16x8 a = *(const f16x8*)&As[((kc * 4 + w) * 64 + lane) * 8];
#pragma unroll
        for (int ct = 0; ct < 8; ct++) {
            f16x8 b = *(const f16x8*)&Wf1[(size_t)(((kc * 8 + ct) * 64) + lane) * 8];
            acc[ct] = __builtin_amdgcn_mfma_f32_16x16x32_f16(a, b, acc[ct], 0, 0, 0);
        }
    }

    __syncthreads();
    ushort16* Ds = (ushort16*)As;      // [64][128]
    const int q = lane >> 4;
#pragma unroll
    for (int ct = 0; ct < 8; ct++)
#pragma unroll
        for (int reg = 0; reg < 4; reg++) {
            int r = w * 16 + q * 4 + reg;
            Ds[r * 128 + ct * 16 + (lane & 15)] = f2bf(acc[ct][reg]);
        }
    __syncthreads();
    {
        int r   = tid >> 2;
        int row = row0 + r;
        if (row < N) {
            int c0 = (tid & 3) * 32;
            const uint4* s = (const uint4*)&Ds[r * 128 + c0];
            uint4* d = (uint4*)(hs1b + (size_t)row * 128 + c0);
#pragma unroll
            for (int i = 0; i < 4; i++) d[i] = s[i];
        }
    }
}

// ================= K3: fused gather1 (inv per edge, relu) -> GEMM2 -> hs2b =================
// Block owns 64 dst nodes. Thread = (node r, quarter q): 32 channels, 64 B/edge loads.
// hs1b holds raw h-tilde; message = inv[s] * h-tilde[s]. Wf2 B-frags from global. LDS 16 KB.

__launch_bounds__(256)
__global__ void k3_fused(const int* __restrict__ rowbeg, const int* __restrict__ rowend,
                         const int* __restrict__ csrs,
                         const ushort16* __restrict__ hs1b, const float* __restrict__ inv,
                         const float* __restrict__ b1, const f16* __restrict__ Wf2,
                         ushort16* __restrict__ hs2b, int N) {
    constexpr int NCT = OUT_C / 16;    // 4
    __shared__ __align__(16) f16 As[4 * 4 * 64 * 8];   // 16 KB

    const int tid  = threadIdx.x;
    const int lane = tid & 63;
    const int w    = tid >> 6;
    const int row0 = blockIdx.x * 64;

    {   // gather phase
        int r = tid >> 2;
        int q = tid & 3;
        int n = row0 + r;
        float acc[32];
#pragma unroll
        for (int j = 0; j < 32; j++) acc[j] = 0.f;

        if (n < N) {
            float ivn = inv[n];
            const ushort16* base = hs1b + (size_t)n * 128 + q * 32;
            uint4 s0 = *(const uint4*)(base);
            uint4 s1 = *(const uint4*)(base + 8);
            uint4 s2 = *(const uint4*)(base + 16);
            uint4 s3 = *(const uint4*)(base + 24);
            acc_row_s(s0, ivn, acc);      acc_row_s(s1, ivn, acc + 8);
            acc_row_s(s2, ivn, acc + 16); acc_row_s(s3, ivn, acc + 24);

            int beg = rowbeg[n], end = rowend[n];
            int i = beg;
            for (; i + 2 <= end; i += 2) {
                int e0 = csrs[i], e1 = csrs[i + 1];
                float v0 = inv[e0], v1 = inv[e1];
                const ushort16* p0 = hs1b + (size_t)e0 * 128 + q * 32;
                const ushort16* p1 = hs1b + (size_t)e1 * 128 + q * 32;
                uint4 a0 = *(const uint4*)(p0);
                uint4 a1 = *(const uint4*)(p0 + 8);
                uint4 a2 = *(const uint4*)(p0 + 16);
                uint4 a3 = *(const uint4*)(p0 + 24);
                uint4 c0 = *(const uint4*)(p1);
                uint4 c1 = *(const uint4*)(p1 + 8);
                uint4 c2 = *(const uint4*)(p1 + 16);
                uint4 c3 = *(const uint4*)(p1 + 24);
                acc_row_s(a0, v0, acc);      acc_row_s(a1, v0, acc + 8);
                acc_row_s(a2, v0, acc + 16); acc_row_s(a3, v0, acc + 24);
                acc_row_s(c0, v1, acc);      acc_row_s(c1, v1, acc + 8);
                acc_row_s(c2, v1, acc + 16); acc_row_s(c3, v1, acc + 24);
            }
            if (i < end) {
                int e0 = csrs[i];
                float v0 = inv[e0];
                const ushort16* p0 = hs1b + (size_t)e0 * 128 + q * 32;
                uint4 a0 = *(const uint4*)(p0);
                uint4 a1 = *(const uint4*)(p0 + 8);
                uint4 a2 = *(const uint4*)(p0 + 16);
                uint4 a3 = *(const uint4*)(p0 + 24);
                acc_row_s(a0, v0, acc);      acc_row_s(a1, v0, acc + 8);
                acc_row_s(a2, v0, acc + 16); acc_row_s(a3, v0, acc + 24);
            }

#pragma unroll
            for (int j = 0; j < 32; j++)
                acc[j] = fmaxf(fmaf(ivn, acc[j], b1[q * 32 + j]), 0.f);
        }

        int ws_ = r >> 4, r15 = r & 15;
#pragma unroll
        for (int i8 = 0; i8 < 4; i8++) {
            f16 h[8];
#pragma unroll
            for (int j = 0; j < 8; j++) h[j] = (f16)acc[i8 * 8 + j];
            int slot = ((q * 4 + ws_) * 64 + (i8 * 16 + r15)) * 8;
            *(uint4*)(As + slot) = *(const uint4*)h;
        }
    }
    __syncthreads();

    f32x4 acc2[NCT];
#pragma unroll
    for (int c = 0; c < NCT; c++) acc2[c] = (f32x4){0.f, 0.f, 0.f, 0.f};
#pragma unroll
    for (int kc = 0; kc < 4; kc++) {
        f16x8 a = *(const f16x8*)&As[((kc * 4 + w) * 64 + lane) * 8];
#pragma unroll
        for (int ct = 0; ct < NCT; ct++) {
            f16x8 b = *(const f16x8*)&Wf2[(size_t)(((kc * NCT + ct) * 64) + lane) * 8];
            acc2[ct] = __builtin_amdgcn_mfma_f32_16x16x32_f16(a, b, acc2[ct], 0, 0, 0);
        }
    }

    __syncthreads();
    ushort16* Ds = (ushort16*)As;      // [64][64]
    const int q2 = lane >> 4;
    float iv2[4];
#pragma unroll
    for (int reg = 0; reg < 4; reg++) {
        int row = row0 + w * 16 + q2 * 4 + reg;
        iv2[reg] = (row < N) ? inv[row] : 0.f;
    }
#pragma unroll
    for (int ct = 0; ct < NCT; ct++)
#pragma unroll
        for (int reg = 0; reg < 4; reg++) {
            int r = w * 16 + q2 * 4 + reg;
            Ds[r * 64 + ct * 16 + (lane & 15)] = f2bf(acc2[ct][reg] * iv2[reg]);
        }
    __syncthreads();
    {
        int r   = tid >> 2;
        int row = row0 + r;
        if (row < N) {
            int c0 = (tid & 3) * 16;
            const uint4* s = (const uint4*)&Ds[r * 64 + c0];
            uint4* d = (uint4*)(hs2b + (size_t)row * 64 + c0);
#pragma unroll
            for (int i = 0; i < 2; i++) d[i] = s[i];
        }
    }
}

// ================= K4: final gather (layer 2) -> fp32 out =================

template <int C, bool RELU>
__launch_bounds__(256)
__global__ void gather_agg_bf16(const int* __restrict__ rowbeg, const int* __restrict__ rowend,
                                const int* __restrict__ csr_src,
                                const ushort16* __restrict__ hsb, const float* __restrict__ inv,
                                const float* __restrict__ b, float* __restrict__ out, int N) {
    constexpr int TPN = C / 8;
    constexpr int NPB = 256 / TPN;
    int n    = blockIdx.x * NPB + threadIdx.x / TPN;
    int lane = threadIdx.x % TPN;
    if (n >= N) return;
    int c8 = lane * 8;

    float acc[8];
    {
        uint4 raw = *(const uint4*)(hsb + (size_t)n * C + c8);
        unpack2(raw.x, acc[0], acc[1]);
        unpack2(raw.y, acc[2], acc[3]);
        unpack2(raw.z, acc[4], acc[5]);
        unpack2(raw.w, acc[6], acc[7]);
    }

    int beg = rowbeg[n];
    int end = rowend[n];
    int i = beg;
    for (; i + 4 <= end; i += 4) {
        int s0 = csr_src[i];
        int s1 = csr_src[i + 1];
        int s2 = csr_src[i + 2];
        int s3 = csr_src[i + 3];
        uint4 r0 = *(const uint4*)(hsb + (size_t)s0 * C + c8);
        uint4 r1 = *(const uint4*)(hsb + (size_t)s1 * C + c8);
        uint4 r2 = *(const uint4*)(hsb + (size_t)s2 * C + c8);
        uint4 r3 = *(const uint4*)(hsb + (size_t)s3 * C + c8);
        acc_row(r0, acc); acc_row(r1, acc); acc_row(r2, acc); acc_row(r3, acc);
    }
    for (; i < end; i++) {
        uint4 r0 = *(const uint4*)(hsb + (size_t)csr_src[i] * C + c8);
        acc_row(r0, acc);
    }

    float iv = inv[n];
    float4 b0 = *(const float4*)(b + c8);
    float4 b1 = *(const float4*)(b + c8 + 4);
    float r[8];
    r[0] = fmaf(iv, acc[0], b0.x); r[1] = fmaf(iv, acc[1], b0.y);
    r[2] = fmaf(iv, acc[2], b0.z); r[3] = fmaf(iv, acc[3], b0.w);
    r[4] = fmaf(iv, acc[4], b1.x); r[5] = fmaf(iv, acc[5], b1.y);
    r[6] = fmaf(iv, acc[6], b1.z); r[7] = fmaf(iv, acc[7], b1.w);
    if (RELU) {
#pragma unroll
        for (int j = 0; j < 8; j++) r[j] = fmaxf(r[j], 0.f);
    }
    float* po = out + (size_t)n * C + c8;
    *(float4*)(po)     = make_float4(r[0], r[1], r[2], r[3]);
    *(float4*)(po + 4) = make_float4(r[4], r[5], r[6], r[7]);
}

extern "C" void kernel_launch(void* const* d_in, const int* in_sizes, int n_in,
                              void* d_out, int out_size, void* d_ws, size_t ws_size,
                              hipStream_t stream) {
    const float* x  = (const float*)d_in[0];
    const int*   ei = (const int*)d_in[1];
    const float* W1 = (const float*)d_in[2];
    const float* b1 = (const float*)d_in[3];
    const float* W2 = (const float*)d_in[4];
    const float* b2 = (const float*)d_in[5];
    float* out = (float*)d_out;

    const int N = in_sizes[0] / IN_C;    // 100000 (<= 131072 for src packing)
    const int E = in_sizes[1] / 2;       // 1600000
    const int* src = ei;
    const int* dst = ei + E;
    const int nbuck  = (N + BSPAN - 1) / BSPAN;     // 391
    const int nchunk = (E + ACHUNK - 1) / ACHUNK;   // 391
    const int ntile  = (N + 63) / 64;               // 1563
    const int wpb    = (4 * (HID_C/16 + OUT_C/16) * 64 + 255) / 256;   // 12

    // workspace layout
    char* ws = (char*)d_ws;
    auto align_up = [](size_t v) { return (v + 1023) & ~(size_t)1023; };
    size_t off = 0;
    int*      bucketCur = (int*)(ws + off);      off += align_up((size_t)nbuck * sizeof(int));
    float*    inv       = (float*)(ws + off);    off += align_up((size_t)N * sizeof(float));
    int*      rowbeg    = (int*)(ws + off);      off += align_up((size_t)N * sizeof(int));
    int*      rowend    = (int*)(ws + off);      off += align_up((size_t)N * sizeof(int));
    uint32*   binned    = (uint32*)(ws + off);   off += align_up((size_t)nbuck * BCAP * sizeof(uint32));
    int*      csrs      = (int*)(ws + off);      off += align_up((size_t)nbuck * BCAP * sizeof(int));
    f16*      Wf1       = (f16*)(ws + off);      off += align_up((size_t)4 * (HID_C/16) * 64 * 8 * sizeof(f16));
    f16*      Wf2       = (f16*)(ws + off);      off += align_up((size_t)4 * (OUT_C/16) * 64 * 8 * sizeof(f16));
    ushort16* hs1b      = (ushort16*)(ws + off); off += align_up((size_t)N * HID_C * sizeof(ushort16));
    ushort16* hs2b      = (ushort16*)(ws + off); off += align_up((size_t)N * OUT_C * sizeof(ushort16));

    hipMemsetAsync(bucketCur, 0, (size_t)nbuck * sizeof(int), stream);

    // K1: binning || weight swizzle
    k1_bin_wprep<<<nchunk + wpb, 256, 0, stream>>>(
        src, dst, bucketCur, binned, W1, Wf1, W2, Wf2, E, nbuck, nchunk);

    // K2: bucket CSR || gemm1 (raw)
    k2_csr_gemm1<<<nbuck + ntile, 256, 0, stream>>>(
        binned, bucketCur, csrs, rowbeg, rowend, inv, x, Wf1, hs1b, N, nbuck);

    // K3: fused gather1 (+inv per edge, relu) -> GEMM2
    k3_fused<<<ntile, 256, 0, stream>>>(
        rowbeg, rowend, csrs, hs1b, inv, b1, Wf2, hs2b, N);

    // K4: final gather
    {
        constexpr int NPB = 256 / (OUT_C / 8);
        gather_agg_bf16<OUT_C, false><<<(N + NPB - 1) / NPB, 256, 0, stream>>>(
            rowbeg, rowend, csrs, hs2b, inv, b2, out, N);
    }
}